// Round 6
// baseline (598.241 us; speedup 1.0000x reference)
//
#include <hip/hip_runtime.h>
#include <cstdint>

#define DEVFN __device__ __forceinline__

constexpr int B_ = 8, N_ = 16384, NP_ = 2048, NS_ = 32;
constexpr int S_ = B_ * NP_ * NS_;         // 524288 samples
constexpr float INV_CNT = 1.0f / 524288.0f;

typedef __attribute__((ext_vector_type(8))) short bf8_t;   // 8 bf16 = 4 VGPR
typedef __attribute__((ext_vector_type(4))) float f4_t;
#define MFMA16(A, Bv, C) __builtin_amdgcn_mfma_f32_16x16x32_bf16(A, Bv, C, 0, 0, 0)

union u4s8 { uint4 u; unsigned short s[8]; };

// ---------- helpers ----------
DEVFN unsigned long long wredmin64(unsigned long long v) {
  for (int o = 32; o; o >>= 1) { unsigned long long u = __shfl_xor(v, o); v = u < v ? u : v; }
  return v;
}
// d2 exactly as reference (KEEP: passing): (sqq+sqp) - 2*dot, dot = sequential mul/add
DEVFN float d2_ref(float4 q, float4 p) {
  float dot = __fadd_rn(__fadd_rn(__fmul_rn(q.x, p.x), __fmul_rn(q.y, p.y)), __fmul_rn(q.z, p.z));
  return __fsub_rn(__fadd_rn(q.w, p.w), __fadd_rn(dot, dot));
}
DEVFN unsigned int fmono(float d) {
  unsigned int u = __float_as_uint(d);
  return u ^ ((u >> 31) ? 0xFFFFFFFFu : 0x80000000u);
}
DEVFN unsigned short f2bf(float f) {   // RNE f32 -> bf16
  unsigned int u = __float_as_uint(f);
  u += 0x7FFFu + ((u >> 16) & 1u);
  return (unsigned short)(u >> 16);
}
DEVFN bf8_t ld_bf8(const unsigned short* p) {   // 16B vector load (global or LDS)
  union { uint4 u; bf8_t b; } cv;
  cv.u = *reinterpret_cast<const uint4*>(p);
  return cv.b;
}

// ---------- prep: pack (x,y,z,||p||^2) ----------
__global__ __launch_bounds__(256) void prep_xyzw(const float* __restrict__ xyz, float4* __restrict__ xyzw) {
  int t = blockIdx.x * 256 + threadIdx.x;      // B*N
  int b = t >> 14, n = t & (N_ - 1);
  const float* X = xyz + (size_t)b * 3 * N_;
  float x = X[n], y = X[N_ + n], z = X[2 * N_ + n];
  float sq = __fadd_rn(__fadd_rn(__fmul_rn(x, x), __fmul_rn(y, y)), __fmul_rn(z, z));
  xyzw[t] = make_float4(x, y, z, sq);
}

// ---------- prep: gather centroids + write q output ----------
__global__ __launch_bounds__(256) void prep_q(const int* __restrict__ sidx, const float4* __restrict__ xyzw,
                                              float4* __restrict__ qw, float* __restrict__ out_q) {
  int t = blockIdx.x * 256 + threadIdx.x;      // B*NP
  int b = t >> 11, p = t & (NP_ - 1);
  int n = sidx[p] & (N_ - 1);
  float4 v = xyzw[b * N_ + n];
  qw[t] = v;
  out_q[((size_t)b * 3 + 0) * NP_ + p] = v.x;
  out_q[((size_t)b * 3 + 1) * NP_ + p] = v.y;
  out_q[((size_t)b * 3 + 2) * NP_ + p] = v.z;
}

// ---------- prep: transpose points (B,64,N) -> (B,N,64) bf16 ----------
__global__ __launch_bounds__(256) void transpose_bf16(const float* __restrict__ in, unsigned short* __restrict__ out) {
  __shared__ float tile[32][33];
  int b = blockIdx.x >> 10;
  int rem = blockIdx.x & 1023;
  int c0 = (rem >> 9) << 5;
  int n0 = (rem & 511) << 5;
  int tx = threadIdx.x & 31, ty = threadIdx.x >> 5;   // 32 x 8
#pragma unroll
  for (int jj = 0; jj < 4; jj++) {
    int c = c0 + ty + jj * 8;
    tile[ty + jj * 8][tx] = in[((size_t)b * 64 + c) * N_ + n0 + tx];
  }
  __syncthreads();
#pragma unroll
  for (int jj = 0; jj < 4; jj++) {
    int n = n0 + ty + jj * 8;
    out[((size_t)b * N_ + n) * 64 + c0 + tx] = f2bf(tile[tx][ty + jj * 8]);
  }
}

// ---------- prep: weights -> bf16 (W1 permuted [pts|rel|0] padded to 96) ----------
__global__ __launch_bounds__(256) void prep_w(const float* __restrict__ W1, const float* __restrict__ W2,
                                              const float* __restrict__ W3, unsigned short* __restrict__ W1b,
                                              unsigned short* __restrict__ W2b, unsigned short* __restrict__ W3b) {
  int t = blockIdx.x * 256 + threadIdx.x;
  int stride = gridDim.x * 256;
  for (int e = t; e < 64 * 96; e += stride) {
    int o = e / 96, k = e - o * 96;
    float v = (k < 64) ? W1[o * 67 + 3 + k] : (k < 67 ? W1[o * 67 + (k - 64)] : 0.0f);
    W1b[e] = f2bf(v);
  }
  for (int e = t; e < 64 * 64; e += stride) W2b[e] = f2bf(W2[e]);
  for (int e = t; e < 128 * 64; e += stride) W3b[e] = f2bf(W3[e]);
}

// ---------- exact 32-NN: 16 queries/block, 4 waves split the point range (verified r5) ----------
__global__ __launch_bounds__(256, 4) void knn_kernel(const float4* __restrict__ xyzw,
                                                     const float4* __restrict__ qw,
                                                     int* __restrict__ idx_out) {
  __shared__ float4 Pst[1024];               // 16KB; reused as dmin store (4096 f32)
  __shared__ unsigned short surv[16][256];   // 8KB
  __shared__ float Tsh[16];
  __shared__ int cnt[16];
  int tid = threadIdx.x, wave = tid >> 6, lane = tid & 63;
  int b = blockIdx.x >> 7;                   // 128 blocks per batch
  int q0 = (blockIdx.x & 127) * 16;
  const float4* P = xyzw + b * N_;
  float Qx[16], Qy[16], Qz[16];
#pragma unroll
  for (int j = 0; j < 16; j++) {
    float4 q = qw[b * NP_ + q0 + j];
    Qx[j] = q.x; Qy[j] = q.y; Qz[j] = q.z;
  }
  float dmin[16];
#pragma unroll
  for (int j = 0; j < 16; j++) dmin[j] = 1e30f;
  for (int c = 0; c < N_ / 1024; c++) {
    __syncthreads();
#pragma unroll
    for (int u = 0; u < 4; u++) Pst[tid + u * 256] = P[c * 1024 + tid + u * 256];
    __syncthreads();
#pragma unroll
    for (int t = 0; t < 4; t++) {
      float4 p = Pst[wave * 256 + t * 64 + lane];
      float kx = -2.0f * p.x, ky = -2.0f * p.y, kz = -2.0f * p.z;
#pragma unroll
      for (int j = 0; j < 16; j++) {
        float key = __fmaf_rn(kx, Qx[j], __fmaf_rn(ky, Qy[j], __fmaf_rn(kz, Qz[j], p.w)));
        dmin[j] = fminf(dmin[j], key);
      }
    }
  }
  __syncthreads();
  float* dl = (float*)Pst;
#pragma unroll
  for (int j = 0; j < 16; j++) dl[j * 256 + wave * 64 + lane] = dmin[j];
  if (tid < 16) cnt[tid] = 0;
  __syncthreads();
#pragma unroll 1
  for (int jj = 0; jj < 4; jj++) {
    int j = wave * 4 + jj;
    float v = fminf(fminf(dl[j * 256 + lane], dl[j * 256 + 64 + lane]),
                    fminf(dl[j * 256 + 128 + lane], dl[j * 256 + 192 + lane]));
#pragma unroll
    for (int k = 2; k <= 64; k <<= 1)
#pragma unroll
      for (int s = k >> 1; s > 0; s >>= 1) {
        float o = __shfl_xor(v, s);
        bool up = ((lane & k) == 0);
        bool tmin = (((lane & s) == 0) == up);
        v = tmin ? fminf(v, o) : fmaxf(v, o);
      }
    if (lane == 31) Tsh[j] = v;
  }
  __syncthreads();
  float T[16];
#pragma unroll
  for (int j = 0; j < 16; j++) T[j] = Tsh[j];
  for (int c = 0; c < N_ / 1024; c++) {
    __syncthreads();
#pragma unroll
    for (int u = 0; u < 4; u++) Pst[tid + u * 256] = P[c * 1024 + tid + u * 256];
    __syncthreads();
#pragma unroll 1
    for (int t = 0; t < 4; t++) {
      int n = c * 1024 + wave * 256 + t * 64 + lane;
      float4 p = Pst[wave * 256 + t * 64 + lane];
      float kx = -2.0f * p.x, ky = -2.0f * p.y, kz = -2.0f * p.z;
#pragma unroll
      for (int j = 0; j < 16; j++) {
        float key = __fmaf_rn(kx, Qx[j], __fmaf_rn(ky, Qy[j], __fmaf_rn(kz, Qz[j], p.w)));
        bool pred = key <= T[j];
        unsigned long long mask = __ballot(pred);
        if (mask) {
          int basew;
          if (lane == 0) basew = atomicAdd(&cnt[j], (int)__popcll(mask));
          basew = __shfl(basew, 0);
          if (pred) {
            int off = basew + (int)__popcll(mask & ((1ull << lane) - 1ull));
            if (off < 256) surv[j][off] = (unsigned short)n;
          }
        }
      }
    }
  }
  __syncthreads();
#pragma unroll 1
  for (int jj = 0; jj < 4; jj++) {
    int j = wave * 4 + jj;
    float4 Q = qw[b * NP_ + q0 + j];
    int m = cnt[j] < 256 ? cnt[j] : 256;
    if (m <= 64) {
      unsigned long long v = ~0ull;
      if (lane < m) {
        int n = surv[j][lane];
        float4 p = P[n];
        float d2 = d2_ref(Q, p);
        v = ((unsigned long long)fmono(d2) << 32) | (unsigned int)n;
      }
#pragma unroll
      for (int k = 2; k <= 64; k <<= 1)
#pragma unroll
        for (int s = k >> 1; s > 0; s >>= 1) {
          unsigned long long o = __shfl_xor(v, s);
          bool up = ((lane & k) == 0);
          bool tmin = (((lane & s) == 0) == up);
          unsigned long long lo = v < o ? v : o;
          unsigned long long hi = v < o ? o : v;
          v = tmin ? lo : hi;
        }
      if (lane < 32) idx_out[(b * NP_ + q0 + j) * NS_ + lane] = (int)(v & 0xFFFFu);
    } else {
      unsigned long long k4[4];
#pragma unroll
      for (int t = 0; t < 4; t++) {
        int ii = t * 64 + lane;
        k4[t] = ~0ull;
        if (ii < m) {
          int n = surv[j][ii];
          float4 p = P[n];
          float d2 = d2_ref(Q, p);
          k4[t] = ((unsigned long long)fmono(d2) << 32) | (unsigned int)n;
        }
      }
      int keep = 0;
      for (int r = 0; r < 32; r++) {
        unsigned long long loc = k4[0];
        loc = k4[1] < loc ? k4[1] : loc;
        loc = k4[2] < loc ? k4[2] : loc;
        loc = k4[3] < loc ? k4[3] : loc;
        unsigned long long km = wredmin64(loc);
#pragma unroll
        for (int t = 0; t < 4; t++) if (k4[t] == km) k4[t] = ~0ull;
        if (lane == r) keep = (int)(km & 0xFFFFu);
      }
      if (lane < 32) idx_out[(b * NP_ + q0 + j) * NS_ + lane] = keep;
    }
  }
}

// ============ wave-synchronous materialized pipeline (1 wave = 1 centroid = 32 rows) ============
// No block barriers in the main loop; LDS transpose through a private per-wave 4KB slice.
// Intra-wave LDS RAW is ordered by HW (per-wave DS queue); wave_barrier pins compiler order.

// fused1: gather + GEMM1 -> stats1, write h1 (pre-BN, bf16) coalesced
__global__ __launch_bounds__(256, 4) void fused1_mat(
    const int* __restrict__ idx, const float4* __restrict__ xyzw, const float4* __restrict__ qw,
    const unsigned short* __restrict__ pTb, const unsigned short* __restrict__ W1b,
    const float* __restrict__ b1, float* __restrict__ statsOut, unsigned short* __restrict__ h) {
  __shared__ unsigned short W1L[64 * 104];
  __shared__ unsigned short hb[4][32 * 64];
  __shared__ float sAcc[128];
  int tid = threadIdx.x;
  int w = tid >> 6, l = tid & 63;
  int c16 = l & 15, g = l >> 4;
  for (int e = tid; e < 64 * 12; e += 256) {
    int r = e / 12, c = e % 12;
    *(uint4*)&W1L[r * 104 + c * 8] = *(const uint4*)&W1b[r * 96 + c * 8];
  }
  float rb1[4];
#pragma unroll
  for (int j = 0; j < 4; j++) rb1[j] = b1[j * 16 + c16];
  float st1[4] = {0, 0, 0, 0}, st2[4] = {0, 0, 0, 0};
  __syncthreads();
  unsigned short* hw = hb[w];
  for (int cen = blockIdx.x * 4 + w; cen < B_ * NP_; cen += gridDim.x * 4) {
    int b = cen >> 11;
    float4 Q = qw[cen];
#pragma unroll
    for (int rh = 0; rh < 2; rh++) {
      int s = cen * 32 + rh * 16 + c16;
      int n = idx[s] & (N_ - 1);
      const unsigned short* arow = pTb + (((size_t)(b << 14) + n) << 6);
      bf8_t a0 = ld_bf8(arow + g * 8);
      bf8_t a1 = ld_bf8(arow + 32 + g * 8);
      float4 P = xyzw[(b << 14) + n];
      bf8_t a2 = {0, 0, 0, 0, 0, 0, 0, 0};
      if (g == 0) {
        a2[0] = (short)f2bf(P.x - Q.x);
        a2[1] = (short)f2bf(P.y - Q.y);
        a2[2] = (short)f2bf(P.z - Q.z);
      }
      f4_t acc[4];
#pragma unroll
      for (int j = 0; j < 4; j++) {
        bf8_t w0 = ld_bf8(&W1L[(j * 16 + c16) * 104 + 0 * 32 + g * 8]);
        bf8_t w1 = ld_bf8(&W1L[(j * 16 + c16) * 104 + 1 * 32 + g * 8]);
        bf8_t w2 = ld_bf8(&W1L[(j * 16 + c16) * 104 + 2 * 32 + g * 8]);
        acc[j] = (f4_t){0.0f, 0.0f, 0.0f, 0.0f};
        acc[j] = MFMA16(a0, w0, acc[j]);
        acc[j] = MFMA16(a1, w1, acc[j]);
        acc[j] = MFMA16(a2, w2, acc[j]);
      }
#pragma unroll
      for (int j = 0; j < 4; j++)
#pragma unroll
        for (int r = 0; r < 4; r++) {
          float hv = acc[j][r] + rb1[j];
          st1[j] += hv; st2[j] += hv * hv;
          int row = rh * 16 + g * 4 + r, ch = j * 16 + c16;
          hw[row * 64 + (((ch >> 3) ^ (row & 7)) << 3) + (ch & 7)] = f2bf(hv);
        }
    }
    __builtin_amdgcn_wave_barrier();
#pragma unroll
    for (int rh = 0; rh < 2; rh++) {
      int rr = rh * 16 + c16;
      uint4 v0 = *(const uint4*)&hw[rr * 64 + ((g ^ (rr & 7)) << 3)];
      uint4 v1 = *(const uint4*)&hw[rr * 64 + (((4 + g) ^ (rr & 7)) << 3)];
      uint4* hd = (uint4*)(h + (((size_t)cen * 32 + rr) << 6));
      hd[g] = v0;
      hd[4 + g] = v1;
    }
    __builtin_amdgcn_wave_barrier();
  }
  __syncthreads();
  if (tid < 128) sAcc[tid] = 0.0f;
  __syncthreads();
#pragma unroll
  for (int j = 0; j < 4; j++) {
    atomicAdd(&sAcc[j * 16 + c16], st1[j]);
    atomicAdd(&sAcc[64 + j * 16 + c16], st2[j]);
  }
  __syncthreads();
  if (tid < 128) atomicAdd(&statsOut[tid], sAcc[tid]);
}

// fused2: read h1 + BN1/ReLU + GEMM2 -> stats2, write h2 in place
__global__ __launch_bounds__(256, 4) void fused2_mat(
    const unsigned short* __restrict__ W2b, const float* __restrict__ g1, const float* __restrict__ be1,
    const float* __restrict__ stats1, const float* __restrict__ b2,
    float* __restrict__ statsOut, unsigned short* __restrict__ h) {
  __shared__ unsigned short W2L[64 * 72];
  __shared__ unsigned short hb[4][32 * 64];
  __shared__ float sa1[64], sd1[64];
  __shared__ float sAcc[128];
  int tid = threadIdx.x;
  int w = tid >> 6, l = tid & 63;
  int c16 = l & 15, g = l >> 4;
  for (int e = tid; e < 64 * 8; e += 256) {
    int r = e >> 3, c = e & 7;
    *(uint4*)&W2L[r * 72 + c * 8] = *(const uint4*)&W2b[r * 64 + c * 8];
  }
  if (tid < 64) {
    float m = stats1[tid] * INV_CNT;
    float v = stats1[64 + tid] * INV_CNT - m * m;
    float a = rsqrtf(v + 1e-5f) * g1[tid];
    sa1[tid] = a;
    sd1[tid] = be1[tid] - m * a;
  }
  float rb2[4];
#pragma unroll
  for (int j = 0; j < 4; j++) rb2[j] = b2[j * 16 + c16];
  float st1[4] = {0, 0, 0, 0}, st2[4] = {0, 0, 0, 0};
  __syncthreads();
  unsigned short* hw = hb[w];
  for (int cen = blockIdx.x * 4 + w; cen < B_ * NP_; cen += gridDim.x * 4) {
#pragma unroll
    for (int rh = 0; rh < 2; rh++) {
      int rr = rh * 16 + c16;
      uint4* hd = (uint4*)(h + (((size_t)cen * 32 + rr) << 6));
      u4s8 c0, c1;
      c0.u = hd[g];
      c1.u = hd[4 + g];
      bf8_t a0f, a1f;
#pragma unroll
      for (int e = 0; e < 8; e++) {
        float x0 = __uint_as_float((unsigned)c0.s[e] << 16);
        float x1 = __uint_as_float((unsigned)c1.s[e] << 16);
        a0f[e] = (short)f2bf(fmaxf(0.0f, fmaf(x0, sa1[g * 8 + e], sd1[g * 8 + e])));
        a1f[e] = (short)f2bf(fmaxf(0.0f, fmaf(x1, sa1[32 + g * 8 + e], sd1[32 + g * 8 + e])));
      }
      f4_t acc[4];
#pragma unroll
      for (int j = 0; j < 4; j++) {
        bf8_t w0 = ld_bf8(&W2L[(j * 16 + c16) * 72 + g * 8]);
        bf8_t w1 = ld_bf8(&W2L[(j * 16 + c16) * 72 + 32 + g * 8]);
        acc[j] = (f4_t){0.0f, 0.0f, 0.0f, 0.0f};
        acc[j] = MFMA16(a0f, w0, acc[j]);
        acc[j] = MFMA16(a1f, w1, acc[j]);
      }
#pragma unroll
      for (int j = 0; j < 4; j++)
#pragma unroll
        for (int r = 0; r < 4; r++) {
          float hv = acc[j][r] + rb2[j];
          st1[j] += hv; st2[j] += hv * hv;
          int row = rh * 16 + g * 4 + r, ch = j * 16 + c16;
          hw[row * 64 + (((ch >> 3) ^ (row & 7)) << 3) + (ch & 7)] = f2bf(hv);
        }
    }
    __builtin_amdgcn_wave_barrier();
#pragma unroll
    for (int rh = 0; rh < 2; rh++) {
      int rr = rh * 16 + c16;
      uint4 v0 = *(const uint4*)&hw[rr * 64 + ((g ^ (rr & 7)) << 3)];
      uint4 v1 = *(const uint4*)&hw[rr * 64 + (((4 + g) ^ (rr & 7)) << 3)];
      uint4* hd = (uint4*)(h + (((size_t)cen * 32 + rr) << 6));
      hd[g] = v0;
      hd[4 + g] = v1;
    }
    __builtin_amdgcn_wave_barrier();
  }
  __syncthreads();
  if (tid < 128) sAcc[tid] = 0.0f;
  __syncthreads();
#pragma unroll
  for (int j = 0; j < 4; j++) {
    atomicAdd(&sAcc[j * 16 + c16], st1[j]);
    atomicAdd(&sAcc[64 + j * 16 + c16], st2[j]);
  }
  __syncthreads();
  if (tid < 128) atomicAdd(&statsOut[tid], sAcc[tid]);
}

// fused3: read h2 + BN2/ReLU + GEMM3 -> stats3 + per-centroid max/min (all intra-wave)
__global__ __launch_bounds__(256, 4) void fused3_mat(
    const unsigned short* __restrict__ W3b, const float* __restrict__ g2, const float* __restrict__ be2,
    const float* __restrict__ stats2, const float* __restrict__ b3,
    float* __restrict__ statsOut, const unsigned short* __restrict__ h, float* __restrict__ maxmin) {
  __shared__ unsigned short W3L[128 * 72];
  __shared__ float sa2[64], sd2[64];
  __shared__ float sAcc[256];
  int tid = threadIdx.x;
  int w = tid >> 6, l = tid & 63;
  int c16 = l & 15, g = l >> 4;
  for (int e = tid; e < 128 * 8; e += 256) {
    int r = e >> 3, c = e & 7;
    *(uint4*)&W3L[r * 72 + c * 8] = *(const uint4*)&W3b[r * 64 + c * 8];
  }
  if (tid < 64) {
    float m = stats2[tid] * INV_CNT;
    float v = stats2[64 + tid] * INV_CNT - m * m;
    float a = rsqrtf(v + 1e-5f) * g2[tid];
    sa2[tid] = a;
    sd2[tid] = be2[tid] - m * a;
  }
  float rb3[8];
#pragma unroll
  for (int j = 0; j < 8; j++) rb3[j] = b3[j * 16 + c16];
  float st1[8], st2[8];
#pragma unroll
  for (int j = 0; j < 8; j++) { st1[j] = 0.0f; st2[j] = 0.0f; }
  __syncthreads();
  for (int cen = blockIdx.x * 4 + w; cen < B_ * NP_; cen += gridDim.x * 4) {
    float mx[8], mn[8];
#pragma unroll
    for (int j = 0; j < 8; j++) { mx[j] = -1e30f; mn[j] = 1e30f; }
#pragma unroll
    for (int rh = 0; rh < 2; rh++) {
      int rr = rh * 16 + c16;
      const uint4* hd = (const uint4*)(h + (((size_t)cen * 32 + rr) << 6));
      u4s8 c0, c1;
      c0.u = hd[g];
      c1.u = hd[4 + g];
      bf8_t a0f, a1f;
#pragma unroll
      for (int e = 0; e < 8; e++) {
        float x0 = __uint_as_float((unsigned)c0.s[e] << 16);
        float x1 = __uint_as_float((unsigned)c1.s[e] << 16);
        a0f[e] = (short)f2bf(fmaxf(0.0f, fmaf(x0, sa2[g * 8 + e], sd2[g * 8 + e])));
        a1f[e] = (short)f2bf(fmaxf(0.0f, fmaf(x1, sa2[32 + g * 8 + e], sd2[32 + g * 8 + e])));
      }
      f4_t acc[8];
#pragma unroll
      for (int j = 0; j < 8; j++) {
        bf8_t w0 = ld_bf8(&W3L[(j * 16 + c16) * 72 + g * 8]);
        bf8_t w1 = ld_bf8(&W3L[(j * 16 + c16) * 72 + 32 + g * 8]);
        acc[j] = (f4_t){0.0f, 0.0f, 0.0f, 0.0f};
        acc[j] = MFMA16(a0f, w0, acc[j]);
        acc[j] = MFMA16(a1f, w1, acc[j]);
      }
#pragma unroll
      for (int j = 0; j < 8; j++)
#pragma unroll
        for (int r = 0; r < 4; r++) {
          float hv = acc[j][r] + rb3[j];
          st1[j] += hv; st2[j] += hv * hv;
          mx[j] = fmaxf(mx[j], hv); mn[j] = fminf(mn[j], hv);
        }
    }
#pragma unroll
    for (int j = 0; j < 8; j++) {
      mx[j] = fmaxf(mx[j], __shfl_xor(mx[j], 16));
      mx[j] = fmaxf(mx[j], __shfl_xor(mx[j], 32));
      mn[j] = fminf(mn[j], __shfl_xor(mn[j], 16));
      mn[j] = fminf(mn[j], __shfl_xor(mn[j], 32));
    }
    if (l < 16) {
      float2* mm = (float2*)(maxmin + (size_t)cen * 256);
#pragma unroll
      for (int j = 0; j < 8; j++) mm[j * 16 + l] = make_float2(mx[j], mn[j]);
    }
  }
  __syncthreads();
  if (tid < 256) sAcc[tid] = 0.0f;
  __syncthreads();
#pragma unroll
  for (int j = 0; j < 8; j++) {
    atomicAdd(&sAcc[j * 16 + c16], st1[j]);
    atomicAdd(&sAcc[128 + j * 16 + c16], st2[j]);
  }
  __syncthreads();
  if (tid < 256) atomicAdd(&statsOut[tid], sAcc[tid]);
}

// ---------- finalize: BN3 affine on max/min -> (B,128,NP) ----------
__global__ __launch_bounds__(256) void finalize_kernel(const float* __restrict__ maxmin,
                                                       const float* __restrict__ stats3,
                                                       const float* __restrict__ g3, const float* __restrict__ be3,
                                                       float* __restrict__ out_np) {
  int o = blockIdx.x * 256 + threadIdx.x;   // B*128*NP
  int p = o & 2047, ch = (o >> 11) & 127, b = o >> 18;
  float m = stats3[ch] * INV_CNT;
  float v = stats3[128 + ch] * INV_CNT - m * m;
  float a = rsqrtf(v + 1e-5f) * g3[ch];
  float d = be3[ch] - m * a;
  size_t g = (size_t)(b * 2048 + p);
  float hi = maxmin[g * 256 + ch * 2 + 0];
  float lo = maxmin[g * 256 + ch * 2 + 1];
  out_np[o] = fmaf(a, (a >= 0.0f ? hi : lo), d);
}

// ---------- launcher ----------
extern "C" void kernel_launch(void* const* d_in, const int* in_sizes, int n_in,
                              void* d_out, int out_size, void* d_ws, size_t ws_size,
                              hipStream_t stream) {
  const float* xyz = (const float*)d_in[0];
  const float* points = (const float*)d_in[1];
  const int* sidx = (const int*)d_in[2];
  const float* W1 = (const float*)d_in[3];
  const float* b1 = (const float*)d_in[4];
  const float* g1 = (const float*)d_in[5];
  const float* be1 = (const float*)d_in[6];
  const float* W2 = (const float*)d_in[7];
  const float* b2 = (const float*)d_in[8];
  const float* g2 = (const float*)d_in[9];
  const float* be2 = (const float*)d_in[10];
  const float* W3 = (const float*)d_in[11];
  const float* b3 = (const float*)d_in[12];
  const float* g3 = (const float*)d_in[13];
  const float* be3 = (const float*)d_in[14];

  float* out_q = (float*)d_out;
  float* out_np = (float*)d_out + (size_t)B_ * 3 * NP_;

  char* ws = (char*)d_ws;
  float* stats1 = (float*)(ws + 0);      // 128 f32
  float* stats2 = (float*)(ws + 512);    // 128 f32
  float* stats3 = (float*)(ws + 1024);   // 256 f32
  size_t off = 4096;
  float4* xyzw = (float4*)(ws + off); off += (size_t)B_ * N_ * 16;              // 2 MB
  float4* qw = (float4*)(ws + off);   off += (size_t)B_ * NP_ * 16;             // 256 KB
  int* idxb = (int*)(ws + off);       off += (size_t)B_ * NP_ * NS_ * 4;        // 2 MB
  unsigned short* pTb = (unsigned short*)(ws + off); off += (size_t)B_ * N_ * 64 * 2;  // 16 MB
  unsigned short* W1b = (unsigned short*)(ws + off); off += 64 * 96 * 2;
  unsigned short* W2b = (unsigned short*)(ws + off); off += 64 * 64 * 2;
  unsigned short* W3b = (unsigned short*)(ws + off); off += 128 * 64 * 2;
  float* maxmin = (float*)(ws + off);  off += (size_t)B_ * NP_ * 128 * 2 * 4;   // 16 MB
  unsigned short* hG = (unsigned short*)(ws + off); off += (size_t)S_ * 64 * 2; // 64 MiB

  hipMemsetAsync(ws, 0, 4096, stream);
  prep_xyzw<<<B_ * N_ / 256, 256, 0, stream>>>(xyz, xyzw);
  prep_q<<<B_ * NP_ / 256, 256, 0, stream>>>(sidx, xyzw, qw, out_q);
  transpose_bf16<<<B_ * 2 * (N_ / 32), 256, 0, stream>>>(points, pTb);
  prep_w<<<72, 256, 0, stream>>>(W1, W2, W3, W1b, W2b, W3b);
  knn_kernel<<<B_ * (NP_ / 16), 256, 0, stream>>>(xyzw, qw, idxb);
  fused1_mat<<<2048, 256, 0, stream>>>(idxb, xyzw, qw, pTb, W1b, b1, stats1, hG);
  fused2_mat<<<2048, 256, 0, stream>>>(W2b, g1, be1, stats1, b2, stats2, hG);
  fused3_mat<<<2048, 256, 0, stream>>>(W3b, g2, be2, stats2, b3, stats3, hG, maxmin);
  finalize_kernel<<<(B_ * 128 * NP_) / 256, 256, 0, stream>>>(maxmin, stats3, g3, be3, out_np);
}

// Round 9
// 524.955 us; speedup vs baseline: 1.1396x; 1.1396x over previous
//
#include <hip/hip_runtime.h>
#include <cstdint>

#define DEVFN __device__ __forceinline__

constexpr int B_ = 8, N_ = 16384, NP_ = 2048, NS_ = 32;
constexpr int S_ = B_ * NP_ * NS_;         // 524288 samples
constexpr float INV_CNT = 1.0f / 524288.0f;

typedef __attribute__((ext_vector_type(8))) short bf8_t;   // 8 bf16 = 4 VGPR
typedef __attribute__((ext_vector_type(4))) float f4_t;
#define MFMA16(A, Bv, C) __builtin_amdgcn_mfma_f32_16x16x32_bf16(A, Bv, C, 0, 0, 0)

union u4s8 { uint4 u; unsigned short s[8]; };

// ---------- helpers ----------
DEVFN unsigned long long wredmin64(unsigned long long v) {
  for (int o = 32; o; o >>= 1) { unsigned long long u = __shfl_xor(v, o); v = u < v ? u : v; }
  return v;
}
// d2 exactly as reference (KEEP: passing): (sqq+sqp) - 2*dot, dot = sequential mul/add
DEVFN float d2_ref(float4 q, float4 p) {
  float dot = __fadd_rn(__fadd_rn(__fmul_rn(q.x, p.x), __fmul_rn(q.y, p.y)), __fmul_rn(q.z, p.z));
  return __fsub_rn(__fadd_rn(q.w, p.w), __fadd_rn(dot, dot));
}
DEVFN unsigned int fmono(float d) {
  unsigned int u = __float_as_uint(d);
  return u ^ ((u >> 31) ? 0xFFFFFFFFu : 0x80000000u);
}
DEVFN unsigned short f2bf(float f) {   // RNE f32 -> bf16
  unsigned int u = __float_as_uint(f);
  u += 0x7FFFu + ((u >> 16) & 1u);
  return (unsigned short)(u >> 16);
}
DEVFN bf8_t ld_bf8(const unsigned short* p) {   // 16B vector load (global or LDS)
  union { uint4 u; bf8_t b; } cv;
  cv.u = *reinterpret_cast<const uint4*>(p);
  return cv.b;
}

// ---------- prep: pack (x,y,z,||p||^2) ----------
__global__ __launch_bounds__(256) void prep_xyzw(const float* __restrict__ xyz, float4* __restrict__ xyzw) {
  int t = blockIdx.x * 256 + threadIdx.x;      // B*N
  int b = t >> 14, n = t & (N_ - 1);
  const float* X = xyz + (size_t)b * 3 * N_;
  float x = X[n], y = X[N_ + n], z = X[2 * N_ + n];
  float sq = __fadd_rn(__fadd_rn(__fmul_rn(x, x), __fmul_rn(y, y)), __fmul_rn(z, z));
  xyzw[t] = make_float4(x, y, z, sq);
}

// ---------- prep: gather centroids + write q output ----------
__global__ __launch_bounds__(256) void prep_q(const int* __restrict__ sidx, const float4* __restrict__ xyzw,
                                              float4* __restrict__ qw, float* __restrict__ out_q) {
  int t = blockIdx.x * 256 + threadIdx.x;      // B*NP
  int b = t >> 11, p = t & (NP_ - 1);
  int n = sidx[p] & (N_ - 1);
  float4 v = xyzw[b * N_ + n];
  qw[t] = v;
  out_q[((size_t)b * 3 + 0) * NP_ + p] = v.x;
  out_q[((size_t)b * 3 + 1) * NP_ + p] = v.y;
  out_q[((size_t)b * 3 + 2) * NP_ + p] = v.z;
}

// ---------- prep: transpose points (B,64,N) -> (B,N,64) bf16 ----------
__global__ __launch_bounds__(256) void transpose_bf16(const float* __restrict__ in, unsigned short* __restrict__ out) {
  __shared__ float tile[32][33];
  int b = blockIdx.x >> 10;
  int rem = blockIdx.x & 1023;
  int c0 = (rem >> 9) << 5;
  int n0 = (rem & 511) << 5;
  int tx = threadIdx.x & 31, ty = threadIdx.x >> 5;   // 32 x 8
#pragma unroll
  for (int jj = 0; jj < 4; jj++) {
    int c = c0 + ty + jj * 8;
    tile[ty + jj * 8][tx] = in[((size_t)b * 64 + c) * N_ + n0 + tx];
  }
  __syncthreads();
#pragma unroll
  for (int jj = 0; jj < 4; jj++) {
    int n = n0 + ty + jj * 8;
    out[((size_t)b * N_ + n) * 64 + c0 + tx] = f2bf(tile[tx][ty + jj * 8]);
  }
}

// ---------- prep: weights -> bf16 (W1 permuted [pts|rel|0] padded to 96) ----------
__global__ __launch_bounds__(256) void prep_w(const float* __restrict__ W1, const float* __restrict__ W2,
                                              const float* __restrict__ W3, unsigned short* __restrict__ W1b,
                                              unsigned short* __restrict__ W2b, unsigned short* __restrict__ W3b) {
  int t = blockIdx.x * 256 + threadIdx.x;
  int stride = gridDim.x * 256;
  for (int e = t; e < 64 * 96; e += stride) {
    int o = e / 96, k = e - o * 96;
    float v = (k < 64) ? W1[o * 67 + 3 + k] : (k < 67 ? W1[o * 67 + (k - 64)] : 0.0f);
    W1b[e] = f2bf(v);
  }
  for (int e = t; e < 64 * 64; e += stride) W2b[e] = f2bf(W2[e]);
  for (int e = t; e < 128 * 64; e += stride) W3b[e] = f2bf(W3[e]);
}

// ---------- exact 32-NN, split-K: 2 blocks per 16-query group, each scans 8192 pts ----------
// Each block emits its half's exact top-32 as sorted u64 (fmono(d2)<<32 | idx) candidates.
__global__ __launch_bounds__(256, 4) void knn_kernel(const float4* __restrict__ xyzw,
                                                     const float4* __restrict__ qw,
                                                     unsigned long long* __restrict__ cand) {
  __shared__ float4 Pst[1024];               // 16KB; reused as dmin store
  __shared__ unsigned short surv[16][256];   // 8KB
  __shared__ float Tsh[16];
  __shared__ int cnt[16];
  int tid = threadIdx.x, wave = tid >> 6, lane = tid & 63;
  int half = blockIdx.x & 1;
  int grp = (blockIdx.x >> 1) & 127;
  int b = blockIdx.x >> 8;
  int q0 = grp * 16;
  int pbase = half * 8192;
  const float4* P = xyzw + b * N_;
  float Qx[16], Qy[16], Qz[16];
#pragma unroll
  for (int j = 0; j < 16; j++) {
    float4 q = qw[b * NP_ + q0 + j];
    Qx[j] = q.x; Qy[j] = q.y; Qz[j] = q.z;
  }
  // pass 1: per-lane min key over this half; each wave covers its quarter of each chunk
  float dmin[16];
#pragma unroll
  for (int j = 0; j < 16; j++) dmin[j] = 1e30f;
  for (int c = 0; c < 8; c++) {
    __syncthreads();
#pragma unroll
    for (int u = 0; u < 4; u++) Pst[tid + u * 256] = P[pbase + c * 1024 + tid + u * 256];
    __syncthreads();
#pragma unroll
    for (int t = 0; t < 4; t++) {
      float4 p = Pst[wave * 256 + t * 64 + lane];
      float kx = -2.0f * p.x, ky = -2.0f * p.y, kz = -2.0f * p.z;
#pragma unroll
      for (int j = 0; j < 16; j++) {
        float key = __fmaf_rn(kx, Qx[j], __fmaf_rn(ky, Qy[j], __fmaf_rn(kz, Qz[j], p.w)));
        dmin[j] = fminf(dmin[j], key);
      }
    }
  }
  __syncthreads();
  float* dl = (float*)Pst;
#pragma unroll
  for (int j = 0; j < 16; j++) dl[j * 256 + wave * 64 + lane] = dmin[j];
  if (tid < 16) cnt[tid] = 0;
  __syncthreads();
  // T = 32nd smallest of 64 combined lane-mins (each over 128 pts of this half)
#pragma unroll 1
  for (int jj = 0; jj < 4; jj++) {
    int j = wave * 4 + jj;
    float v = fminf(fminf(dl[j * 256 + lane], dl[j * 256 + 64 + lane]),
                    fminf(dl[j * 256 + 128 + lane], dl[j * 256 + 192 + lane]));
#pragma unroll
    for (int k = 2; k <= 64; k <<= 1)
#pragma unroll
      for (int s = k >> 1; s > 0; s >>= 1) {
        float o = __shfl_xor(v, s);
        bool up = ((lane & k) == 0);
        bool tmin = (((lane & s) == 0) == up);
        v = tmin ? fminf(v, o) : fmaxf(v, o);
      }
    if (lane == 31) Tsh[j] = v;
  }
  __syncthreads();
  float T[16];
#pragma unroll
  for (int j = 0; j < 16; j++) T[j] = Tsh[j];
  // pass 2: filter into block-shared survivor lists
  for (int c = 0; c < 8; c++) {
    __syncthreads();
#pragma unroll
    for (int u = 0; u < 4; u++) Pst[tid + u * 256] = P[pbase + c * 1024 + tid + u * 256];
    __syncthreads();
#pragma unroll 1
    for (int t = 0; t < 4; t++) {
      int n = pbase + c * 1024 + wave * 256 + t * 64 + lane;
      float4 p = Pst[wave * 256 + t * 64 + lane];
      float kx = -2.0f * p.x, ky = -2.0f * p.y, kz = -2.0f * p.z;
#pragma unroll
      for (int j = 0; j < 16; j++) {
        float key = __fmaf_rn(kx, Qx[j], __fmaf_rn(ky, Qy[j], __fmaf_rn(kz, Qz[j], p.w)));
        bool pred = key <= T[j];
        unsigned long long mask = __ballot(pred);
        if (mask) {
          int basew;
          if (lane == 0) basew = atomicAdd(&cnt[j], (int)__popcll(mask));
          basew = __shfl(basew, 0);
          if (pred) {
            int off = basew + (int)__popcll(mask & ((1ull << lane) - 1ull));
            if (off < 256) surv[j][off] = (unsigned short)n;
          }
        }
      }
    }
  }
  __syncthreads();
  // selection: exact reference d2 on survivors, top-32 by (d2, idx); wave owns 4 queries
#pragma unroll 1
  for (int jj = 0; jj < 4; jj++) {
    int j = wave * 4 + jj;
    float4 Q = qw[b * NP_ + q0 + j];
    size_t qbase = (((size_t)(b * NP_ + q0 + j)) << 6) + half * 32;
    int m = cnt[j] < 256 ? cnt[j] : 256;
    if (m <= 64) {
      unsigned long long v = ~0ull;
      if (lane < m) {
        int n = surv[j][lane];
        float4 p = P[n];
        float d2 = d2_ref(Q, p);
        v = ((unsigned long long)fmono(d2) << 32) | (unsigned int)n;
      }
#pragma unroll
      for (int k = 2; k <= 64; k <<= 1)
#pragma unroll
        for (int s = k >> 1; s > 0; s >>= 1) {
          unsigned long long o = __shfl_xor(v, s);
          bool up = ((lane & k) == 0);
          bool tmin = (((lane & s) == 0) == up);
          unsigned long long lo = v < o ? v : o;
          unsigned long long hi = v < o ? o : v;
          v = tmin ? lo : hi;
        }
      if (lane < 32) cand[qbase + lane] = v;
    } else {
      unsigned long long k4[4];
#pragma unroll
      for (int t = 0; t < 4; t++) {
        int ii = t * 64 + lane;
        k4[t] = ~0ull;
        if (ii < m) {
          int n = surv[j][ii];
          float4 p = P[n];
          float d2 = d2_ref(Q, p);
          k4[t] = ((unsigned long long)fmono(d2) << 32) | (unsigned int)n;
        }
      }
      unsigned long long keepk = 0;
      for (int r = 0; r < 32; r++) {
        unsigned long long loc = k4[0];
        loc = k4[1] < loc ? k4[1] : loc;
        loc = k4[2] < loc ? k4[2] : loc;
        loc = k4[3] < loc ? k4[3] : loc;
        unsigned long long km = wredmin64(loc);
#pragma unroll
        for (int t = 0; t < 4; t++) if (k4[t] == km) k4[t] = ~0ull;
        if (lane == r) keepk = km;
      }
      if (lane < 32) cand[qbase + lane] = keepk;
    }
  }
}

// ---------- merge two half-top-32 lists -> final top-32 indices ----------
__global__ __launch_bounds__(256) void knn_merge(const unsigned long long* __restrict__ cand,
                                                 int* __restrict__ idx_out) {
  int wave = threadIdx.x >> 6, lane = threadIdx.x & 63;
  int q = blockIdx.x * 4 + wave;              // B*NP queries
  unsigned long long v = cand[((size_t)q << 6) + lane];
#pragma unroll
  for (int k = 2; k <= 64; k <<= 1)
#pragma unroll
    for (int s = k >> 1; s > 0; s >>= 1) {
      unsigned long long o = __shfl_xor(v, s);
      bool up = ((lane & k) == 0);
      bool tmin = (((lane & s) == 0) == up);
      unsigned long long lo = v < o ? v : o;
      unsigned long long hi = v < o ? o : v;
      v = tmin ? lo : hi;
    }
  if (lane < 32) idx_out[q * NS_ + lane] = (int)(v & 0xFFFFu);
}

// ============ wave-synchronous materialized pipeline (1 wave = 1 centroid = 32 rows) ============
// launch_bounds(256,3): ~170 unified regs -> no scratch spill (r6 lesson: (256,4) forced 64 VGPR + spills).
// Accumulator scalarized: one f4_t per column-tile, consumed immediately.

// fused1: gather + GEMM1 -> stats1, write h1 (pre-BN, bf16) coalesced
__global__ __launch_bounds__(256, 3) void fused1_mat(
    const int* __restrict__ idx, const float4* __restrict__ xyzw, const float4* __restrict__ qw,
    const unsigned short* __restrict__ pTb, const unsigned short* __restrict__ W1b,
    const float* __restrict__ b1, float* __restrict__ statsOut, unsigned short* __restrict__ h) {
  __shared__ unsigned short W1L[64 * 104];
  __shared__ unsigned short hb[4][32 * 64];
  __shared__ float sAcc[128];
  int tid = threadIdx.x;
  int w = tid >> 6, l = tid & 63;
  int c16 = l & 15, g = l >> 4;
  for (int e = tid; e < 64 * 12; e += 256) {
    int r = e / 12, c = e % 12;
    *(uint4*)&W1L[r * 104 + c * 8] = *(const uint4*)&W1b[r * 96 + c * 8];
  }
  float rb1[4];
#pragma unroll
  for (int j = 0; j < 4; j++) rb1[j] = b1[j * 16 + c16];
  float st1[4] = {0, 0, 0, 0}, st2[4] = {0, 0, 0, 0};
  __syncthreads();
  unsigned short* hw = hb[w];
  for (int cen = blockIdx.x * 4 + w; cen < B_ * NP_; cen += gridDim.x * 4) {
    int b = cen >> 11;
    float4 Q = qw[cen];
#pragma unroll 1
    for (int rh = 0; rh < 2; rh++) {
      int s = cen * 32 + rh * 16 + c16;
      int n = idx[s] & (N_ - 1);
      const unsigned short* arow = pTb + (((size_t)(b << 14) + n) << 6);
      bf8_t a0 = ld_bf8(arow + g * 8);
      bf8_t a1 = ld_bf8(arow + 32 + g * 8);
      float4 P = xyzw[(b << 14) + n];
      bf8_t a2 = {0, 0, 0, 0, 0, 0, 0, 0};
      if (g == 0) {
        a2[0] = (short)f2bf(P.x - Q.x);
        a2[1] = (short)f2bf(P.y - Q.y);
        a2[2] = (short)f2bf(P.z - Q.z);
      }
#pragma unroll
      for (int j = 0; j < 4; j++) {
        bf8_t w0 = ld_bf8(&W1L[(j * 16 + c16) * 104 + 0 * 32 + g * 8]);
        bf8_t w1 = ld_bf8(&W1L[(j * 16 + c16) * 104 + 1 * 32 + g * 8]);
        bf8_t w2 = ld_bf8(&W1L[(j * 16 + c16) * 104 + 2 * 32 + g * 8]);
        f4_t acc = (f4_t){0.0f, 0.0f, 0.0f, 0.0f};
        acc = MFMA16(a0, w0, acc);
        acc = MFMA16(a1, w1, acc);
        acc = MFMA16(a2, w2, acc);
#pragma unroll
        for (int r = 0; r < 4; r++) {
          float hv = acc[r] + rb1[j];
          st1[j] += hv; st2[j] += hv * hv;
          int row = rh * 16 + g * 4 + r, ch = j * 16 + c16;
          hw[row * 64 + (((ch >> 3) ^ (row & 7)) << 3) + (ch & 7)] = f2bf(hv);
        }
      }
    }
    __builtin_amdgcn_wave_barrier();
#pragma unroll
    for (int rh = 0; rh < 2; rh++) {
      int rr = rh * 16 + c16;
      uint4 v0 = *(const uint4*)&hw[rr * 64 + ((g ^ (rr & 7)) << 3)];
      uint4 v1 = *(const uint4*)&hw[rr * 64 + (((4 + g) ^ (rr & 7)) << 3)];
      uint4* hd = (uint4*)(h + (((size_t)cen * 32 + rr) << 6));
      hd[g] = v0;
      hd[4 + g] = v1;
    }
    __builtin_amdgcn_wave_barrier();
  }
  __syncthreads();
  if (tid < 128) sAcc[tid] = 0.0f;
  __syncthreads();
#pragma unroll
  for (int j = 0; j < 4; j++) {
    atomicAdd(&sAcc[j * 16 + c16], st1[j]);
    atomicAdd(&sAcc[64 + j * 16 + c16], st2[j]);
  }
  __syncthreads();
  if (tid < 128) atomicAdd(&statsOut[tid], sAcc[tid]);
}

// fused2: read h1 + BN1/ReLU + GEMM2 -> stats2, write h2 in place
__global__ __launch_bounds__(256, 3) void fused2_mat(
    const unsigned short* __restrict__ W2b, const float* __restrict__ g1, const float* __restrict__ be1,
    const float* __restrict__ stats1, const float* __restrict__ b2,
    float* __restrict__ statsOut, unsigned short* __restrict__ h) {
  __shared__ unsigned short W2L[64 * 72];
  __shared__ unsigned short hb[4][32 * 64];
  __shared__ float sa1[64], sd1[64];
  __shared__ float sAcc[128];
  int tid = threadIdx.x;
  int w = tid >> 6, l = tid & 63;
  int c16 = l & 15, g = l >> 4;
  for (int e = tid; e < 64 * 8; e += 256) {
    int r = e >> 3, c = e & 7;
    *(uint4*)&W2L[r * 72 + c * 8] = *(const uint4*)&W2b[r * 64 + c * 8];
  }
  if (tid < 64) {
    float m = stats1[tid] * INV_CNT;
    float v = stats1[64 + tid] * INV_CNT - m * m;
    float a = rsqrtf(v + 1e-5f) * g1[tid];
    sa1[tid] = a;
    sd1[tid] = be1[tid] - m * a;
  }
  float rb2[4];
#pragma unroll
  for (int j = 0; j < 4; j++) rb2[j] = b2[j * 16 + c16];
  float st1[4] = {0, 0, 0, 0}, st2[4] = {0, 0, 0, 0};
  __syncthreads();
  unsigned short* hw = hb[w];
  for (int cen = blockIdx.x * 4 + w; cen < B_ * NP_; cen += gridDim.x * 4) {
#pragma unroll 1
    for (int rh = 0; rh < 2; rh++) {
      int rr = rh * 16 + c16;
      uint4* hd = (uint4*)(h + (((size_t)cen * 32 + rr) << 6));
      u4s8 c0, c1;
      c0.u = hd[g];
      c1.u = hd[4 + g];
      bf8_t a0f, a1f;
#pragma unroll
      for (int e = 0; e < 8; e++) {
        float x0 = __uint_as_float((unsigned)c0.s[e] << 16);
        float x1 = __uint_as_float((unsigned)c1.s[e] << 16);
        a0f[e] = (short)f2bf(fmaxf(0.0f, fmaf(x0, sa1[g * 8 + e], sd1[g * 8 + e])));
        a1f[e] = (short)f2bf(fmaxf(0.0f, fmaf(x1, sa1[32 + g * 8 + e], sd1[32 + g * 8 + e])));
      }
#pragma unroll
      for (int j = 0; j < 4; j++) {
        bf8_t w0 = ld_bf8(&W2L[(j * 16 + c16) * 72 + g * 8]);
        bf8_t w1 = ld_bf8(&W2L[(j * 16 + c16) * 72 + 32 + g * 8]);
        f4_t acc = (f4_t){0.0f, 0.0f, 0.0f, 0.0f};
        acc = MFMA16(a0f, w0, acc);
        acc = MFMA16(a1f, w1, acc);
#pragma unroll
        for (int r = 0; r < 4; r++) {
          float hv = acc[r] + rb2[j];
          st1[j] += hv; st2[j] += hv * hv;
          int row = rh * 16 + g * 4 + r, ch = j * 16 + c16;
          hw[row * 64 + (((ch >> 3) ^ (row & 7)) << 3) + (ch & 7)] = f2bf(hv);
        }
      }
    }
    __builtin_amdgcn_wave_barrier();
#pragma unroll
    for (int rh = 0; rh < 2; rh++) {
      int rr = rh * 16 + c16;
      uint4 v0 = *(const uint4*)&hw[rr * 64 + ((g ^ (rr & 7)) << 3)];
      uint4 v1 = *(const uint4*)&hw[rr * 64 + (((4 + g) ^ (rr & 7)) << 3)];
      uint4* hd = (uint4*)(h + (((size_t)cen * 32 + rr) << 6));
      hd[g] = v0;
      hd[4 + g] = v1;
    }
    __builtin_amdgcn_wave_barrier();
  }
  __syncthreads();
  if (tid < 128) sAcc[tid] = 0.0f;
  __syncthreads();
#pragma unroll
  for (int j = 0; j < 4; j++) {
    atomicAdd(&sAcc[j * 16 + c16], st1[j]);
    atomicAdd(&sAcc[64 + j * 16 + c16], st2[j]);
  }
  __syncthreads();
  if (tid < 128) atomicAdd(&statsOut[tid], sAcc[tid]);
}

// fused3: read h2 + BN2/ReLU + GEMM3 -> stats3 + per-centroid max/min (all intra-wave)
__global__ __launch_bounds__(256, 3) void fused3_mat(
    const unsigned short* __restrict__ W3b, const float* __restrict__ g2, const float* __restrict__ be2,
    const float* __restrict__ stats2, const float* __restrict__ b3,
    float* __restrict__ statsOut, const unsigned short* __restrict__ h, float* __restrict__ maxmin) {
  __shared__ unsigned short W3L[128 * 72];
  __shared__ float sa2[64], sd2[64];
  __shared__ float sAcc[256];
  int tid = threadIdx.x;
  int w = tid >> 6, l = tid & 63;
  int c16 = l & 15, g = l >> 4;
  for (int e = tid; e < 128 * 8; e += 256) {
    int r = e >> 3, c = e & 7;
    *(uint4*)&W3L[r * 72 + c * 8] = *(const uint4*)&W3b[r * 64 + c * 8];
  }
  if (tid < 64) {
    float m = stats2[tid] * INV_CNT;
    float v = stats2[64 + tid] * INV_CNT - m * m;
    float a = rsqrtf(v + 1e-5f) * g2[tid];
    sa2[tid] = a;
    sd2[tid] = be2[tid] - m * a;
  }
  float rb3[8];
#pragma unroll
  for (int j = 0; j < 8; j++) rb3[j] = b3[j * 16 + c16];
  float st1[8], st2[8];
#pragma unroll
  for (int j = 0; j < 8; j++) { st1[j] = 0.0f; st2[j] = 0.0f; }
  __syncthreads();
  for (int cen = blockIdx.x * 4 + w; cen < B_ * NP_; cen += gridDim.x * 4) {
    float mx[8], mn[8];
#pragma unroll
    for (int j = 0; j < 8; j++) { mx[j] = -1e30f; mn[j] = 1e30f; }
#pragma unroll 1
    for (int rh = 0; rh < 2; rh++) {
      int rr = rh * 16 + c16;
      const uint4* hd = (const uint4*)(h + (((size_t)cen * 32 + rr) << 6));
      u4s8 c0, c1;
      c0.u = hd[g];
      c1.u = hd[4 + g];
      bf8_t a0f, a1f;
#pragma unroll
      for (int e = 0; e < 8; e++) {
        float x0 = __uint_as_float((unsigned)c0.s[e] << 16);
        float x1 = __uint_as_float((unsigned)c1.s[e] << 16);
        a0f[e] = (short)f2bf(fmaxf(0.0f, fmaf(x0, sa2[g * 8 + e], sd2[g * 8 + e])));
        a1f[e] = (short)f2bf(fmaxf(0.0f, fmaf(x1, sa2[32 + g * 8 + e], sd2[32 + g * 8 + e])));
      }
#pragma unroll
      for (int j = 0; j < 8; j++) {
        bf8_t w0 = ld_bf8(&W3L[(j * 16 + c16) * 72 + g * 8]);
        bf8_t w1 = ld_bf8(&W3L[(j * 16 + c16) * 72 + 32 + g * 8]);
        f4_t acc = (f4_t){0.0f, 0.0f, 0.0f, 0.0f};
        acc = MFMA16(a0f, w0, acc);
        acc = MFMA16(a1f, w1, acc);
#pragma unroll
        for (int r = 0; r < 4; r++) {
          float hv = acc[r] + rb3[j];
          st1[j] += hv; st2[j] += hv * hv;
          mx[j] = fmaxf(mx[j], hv); mn[j] = fminf(mn[j], hv);
        }
      }
    }
#pragma unroll
    for (int j = 0; j < 8; j++) {
      mx[j] = fmaxf(mx[j], __shfl_xor(mx[j], 16));
      mx[j] = fmaxf(mx[j], __shfl_xor(mx[j], 32));
      mn[j] = fminf(mn[j], __shfl_xor(mn[j], 16));
      mn[j] = fminf(mn[j], __shfl_xor(mn[j], 32));
    }
    if (l < 16) {
      float2* mm = (float2*)(maxmin + (size_t)cen * 256);
#pragma unroll
      for (int j = 0; j < 8; j++) mm[j * 16 + l] = make_float2(mx[j], mn[j]);
    }
  }
  __syncthreads();
  if (tid < 256) sAcc[tid] = 0.0f;
  __syncthreads();
#pragma unroll
  for (int j = 0; j < 8; j++) {
    atomicAdd(&sAcc[j * 16 + c16], st1[j]);
    atomicAdd(&sAcc[128 + j * 16 + c16], st2[j]);
  }
  __syncthreads();
  if (tid < 256) atomicAdd(&statsOut[tid], sAcc[tid]);
}

// ---------- finalize: BN3 affine on max/min -> (B,128,NP) ----------
__global__ __launch_bounds__(256) void finalize_kernel(const float* __restrict__ maxmin,
                                                       const float* __restrict__ stats3,
                                                       const float* __restrict__ g3, const float* __restrict__ be3,
                                                       float* __restrict__ out_np) {
  int o = blockIdx.x * 256 + threadIdx.x;   // B*128*NP
  int p = o & 2047, ch = (o >> 11) & 127, b = o >> 18;
  float m = stats3[ch] * INV_CNT;
  float v = stats3[128 + ch] * INV_CNT - m * m;
  float a = rsqrtf(v + 1e-5f) * g3[ch];
  float d = be3[ch] - m * a;
  size_t g = (size_t)(b * 2048 + p);
  float hi = maxmin[g * 256 + ch * 2 + 0];
  float lo = maxmin[g * 256 + ch * 2 + 1];
  out_np[o] = fmaf(a, (a >= 0.0f ? hi : lo), d);
}

// ---------- launcher ----------
extern "C" void kernel_launch(void* const* d_in, const int* in_sizes, int n_in,
                              void* d_out, int out_size, void* d_ws, size_t ws_size,
                              hipStream_t stream) {
  const float* xyz = (const float*)d_in[0];
  const float* points = (const float*)d_in[1];
  const int* sidx = (const int*)d_in[2];
  const float* W1 = (const float*)d_in[3];
  const float* b1 = (const float*)d_in[4];
  const float* g1 = (const float*)d_in[5];
  const float* be1 = (const float*)d_in[6];
  const float* W2 = (const float*)d_in[7];
  const float* b2 = (const float*)d_in[8];
  const float* g2 = (const float*)d_in[9];
  const float* be2 = (const float*)d_in[10];
  const float* W3 = (const float*)d_in[11];
  const float* b3 = (const float*)d_in[12];
  const float* g3 = (const float*)d_in[13];
  const float* be3 = (const float*)d_in[14];

  float* out_q = (float*)d_out;
  float* out_np = (float*)d_out + (size_t)B_ * 3 * NP_;

  char* ws = (char*)d_ws;
  float* stats1 = (float*)(ws + 0);      // 128 f32
  float* stats2 = (float*)(ws + 512);    // 128 f32
  float* stats3 = (float*)(ws + 1024);   // 256 f32
  size_t off = 4096;
  float4* xyzw = (float4*)(ws + off); off += (size_t)B_ * N_ * 16;              // 2 MB
  float4* qw = (float4*)(ws + off);   off += (size_t)B_ * NP_ * 16;             // 256 KB
  int* idxb = (int*)(ws + off);       off += (size_t)B_ * NP_ * NS_ * 4;        // 2 MB
  unsigned short* pTb = (unsigned short*)(ws + off); off += (size_t)B_ * N_ * 64 * 2;  // 16 MB
  unsigned short* W1b = (unsigned short*)(ws + off); off += 64 * 96 * 2;
  unsigned short* W2b = (unsigned short*)(ws + off); off += 64 * 64 * 2;
  unsigned short* W3b = (unsigned short*)(ws + off); off += 128 * 64 * 2;
  float* maxmin = (float*)(ws + off);  off += (size_t)B_ * NP_ * 128 * 2 * 4;   // 16 MB
  unsigned short* hG = (unsigned short*)(ws + off); off += (size_t)S_ * 64 * 2; // 64 MiB
  // cand (8 MB) overlays maxmin: knn+merge finish before fused3 writes maxmin
  unsigned long long* cand = (unsigned long long*)maxmin;

  hipMemsetAsync(ws, 0, 4096, stream);
  prep_xyzw<<<B_ * N_ / 256, 256, 0, stream>>>(xyz, xyzw);
  prep_q<<<B_ * NP_ / 256, 256, 0, stream>>>(sidx, xyzw, qw, out_q);
  transpose_bf16<<<B_ * 2 * (N_ / 32), 256, 0, stream>>>(points, pTb);
  prep_w<<<72, 256, 0, stream>>>(W1, W2, W3, W1b, W2b, W3b);
  knn_kernel<<<B_ * (NP_ / 16) * 2, 256, 0, stream>>>(xyzw, qw, cand);
  knn_merge<<<B_ * NP_ / 4, 256, 0, stream>>>(cand, idxb);
  fused1_mat<<<2048, 256, 0, stream>>>(idxb, xyzw, qw, pTb, W1b, b1, stats1, hG);
  fused2_mat<<<2048, 256, 0, stream>>>(W2b, g1, be1, stats1, b2, stats2, hG);
  fused3_mat<<<2048, 256, 0, stream>>>(W3b, g2, be2, stats2, b3, stats3, hG, maxmin);
  finalize_kernel<<<(B_ * 128 * NP_) / 256, 256, 0, stream>>>(maxmin, stats3, g3, be3, out_np);
}

// Round 10
// 398.254 us; speedup vs baseline: 1.5022x; 1.3181x over previous
//
#include <hip/hip_runtime.h>
#include <cstdint>

#define DEVFN __device__ __forceinline__

constexpr int B_ = 8, N_ = 16384, NP_ = 2048, NS_ = 32;
constexpr int S_ = B_ * NP_ * NS_;         // 524288 samples
constexpr float INV_CNT = 1.0f / 524288.0f;

typedef __attribute__((ext_vector_type(8))) short bf8_t;   // 8 bf16 = 4 VGPR
typedef __attribute__((ext_vector_type(4))) float f4_t;
#define MFMA16(A, Bv, C) __builtin_amdgcn_mfma_f32_16x16x32_bf16(A, Bv, C, 0, 0, 0)

union u4s8 { uint4 u; unsigned short s[8]; };

// ---------- helpers ----------
DEVFN unsigned long long wredmin64(unsigned long long v) {
  for (int o = 32; o; o >>= 1) { unsigned long long u = __shfl_xor(v, o); v = u < v ? u : v; }
  return v;
}
// d2 exactly as reference (KEEP: passing): (sqq+sqp) - 2*dot, dot = sequential mul/add
DEVFN float d2_ref(float4 q, float4 p) {
  float dot = __fadd_rn(__fadd_rn(__fmul_rn(q.x, p.x), __fmul_rn(q.y, p.y)), __fmul_rn(q.z, p.z));
  return __fsub_rn(__fadd_rn(q.w, p.w), __fadd_rn(dot, dot));
}
DEVFN unsigned int fmono(float d) {
  unsigned int u = __float_as_uint(d);
  return u ^ ((u >> 31) ? 0xFFFFFFFFu : 0x80000000u);
}
DEVFN unsigned short f2bf(float f) {   // RNE f32 -> bf16
  unsigned int u = __float_as_uint(f);
  u += 0x7FFFu + ((u >> 16) & 1u);
  return (unsigned short)(u >> 16);
}
DEVFN float bf2f(unsigned short s) { return __uint_as_float((unsigned)s << 16); }
DEVFN bf8_t ld_bf8(const unsigned short* p) {   // 16B vector load (global or LDS)
  union { uint4 u; bf8_t b; } cv;
  cv.u = *reinterpret_cast<const uint4*>(p);
  return cv.b;
}

// ---------- prep: pack (x,y,z,||p||^2) ----------
__global__ __launch_bounds__(256) void prep_xyzw(const float* __restrict__ xyz, float4* __restrict__ xyzw) {
  int t = blockIdx.x * 256 + threadIdx.x;      // B*N
  int b = t >> 14, n = t & (N_ - 1);
  const float* X = xyz + (size_t)b * 3 * N_;
  float x = X[n], y = X[N_ + n], z = X[2 * N_ + n];
  float sq = __fadd_rn(__fadd_rn(__fmul_rn(x, x), __fmul_rn(y, y)), __fmul_rn(z, z));
  xyzw[t] = make_float4(x, y, z, sq);
}

// ---------- prep: gather centroids + write q output ----------
__global__ __launch_bounds__(256) void prep_q(const int* __restrict__ sidx, const float4* __restrict__ xyzw,
                                              float4* __restrict__ qw, float* __restrict__ out_q) {
  int t = blockIdx.x * 256 + threadIdx.x;      // B*NP
  int b = t >> 11, p = t & (NP_ - 1);
  int n = sidx[p] & (N_ - 1);
  float4 v = xyzw[b * N_ + n];
  qw[t] = v;
  out_q[((size_t)b * 3 + 0) * NP_ + p] = v.x;
  out_q[((size_t)b * 3 + 1) * NP_ + p] = v.y;
  out_q[((size_t)b * 3 + 2) * NP_ + p] = v.z;
}

// ---------- prep: transpose points (B,64,N) -> (B,N,64) bf16 ----------
__global__ __launch_bounds__(256) void transpose_bf16(const float* __restrict__ in, unsigned short* __restrict__ out) {
  __shared__ float tile[32][33];
  int b = blockIdx.x >> 10;
  int rem = blockIdx.x & 1023;
  int c0 = (rem >> 9) << 5;
  int n0 = (rem & 511) << 5;
  int tx = threadIdx.x & 31, ty = threadIdx.x >> 5;   // 32 x 8
#pragma unroll
  for (int jj = 0; jj < 4; jj++) {
    int c = c0 + ty + jj * 8;
    tile[ty + jj * 8][tx] = in[((size_t)b * 64 + c) * N_ + n0 + tx];
  }
  __syncthreads();
#pragma unroll
  for (int jj = 0; jj < 4; jj++) {
    int n = n0 + ty + jj * 8;
    out[((size_t)b * N_ + n) * 64 + c0 + tx] = f2bf(tile[tx][ty + jj * 8]);
  }
}

// ---------- prep: weights -> bf16 (W1 permuted [pts|rel|0] padded to 96) ----------
__global__ __launch_bounds__(256) void prep_w(const float* __restrict__ W1, const float* __restrict__ W2,
                                              const float* __restrict__ W3, unsigned short* __restrict__ W1b,
                                              unsigned short* __restrict__ W2b, unsigned short* __restrict__ W3b) {
  int t = blockIdx.x * 256 + threadIdx.x;
  int stride = gridDim.x * 256;
  for (int e = t; e < 64 * 96; e += stride) {
    int o = e / 96, k = e - o * 96;
    float v = (k < 64) ? W1[o * 67 + 3 + k] : (k < 67 ? W1[o * 67 + (k - 64)] : 0.0f);
    W1b[e] = f2bf(v);
  }
  for (int e = t; e < 64 * 64; e += stride) W2b[e] = f2bf(W2[e]);
  for (int e = t; e < 128 * 64; e += stride) W3b[e] = f2bf(W3[e]);
}

// ---------- exact 32-NN: 16 queries/block, 4 waves split the point range (r5 verbatim, 133us) ----------
__global__ __launch_bounds__(256, 4) void knn_kernel(const float4* __restrict__ xyzw,
                                                     const float4* __restrict__ qw,
                                                     int* __restrict__ idx_out) {
  __shared__ float4 Pst[1024];               // 16KB; reused as dmin store (4096 f32)
  __shared__ unsigned short surv[16][256];   // 8KB
  __shared__ float Tsh[16];
  __shared__ int cnt[16];
  int tid = threadIdx.x, wave = tid >> 6, lane = tid & 63;
  int b = blockIdx.x >> 7;                   // 128 blocks per batch
  int q0 = (blockIdx.x & 127) * 16;
  const float4* P = xyzw + b * N_;
  float Qx[16], Qy[16], Qz[16];
#pragma unroll
  for (int j = 0; j < 16; j++) {
    float4 q = qw[b * NP_ + q0 + j];
    Qx[j] = q.x; Qy[j] = q.y; Qz[j] = q.z;
  }
  float dmin[16];
#pragma unroll
  for (int j = 0; j < 16; j++) dmin[j] = 1e30f;
  for (int c = 0; c < N_ / 1024; c++) {
    __syncthreads();
#pragma unroll
    for (int u = 0; u < 4; u++) Pst[tid + u * 256] = P[c * 1024 + tid + u * 256];
    __syncthreads();
#pragma unroll
    for (int t = 0; t < 4; t++) {
      float4 p = Pst[wave * 256 + t * 64 + lane];
      float kx = -2.0f * p.x, ky = -2.0f * p.y, kz = -2.0f * p.z;
#pragma unroll
      for (int j = 0; j < 16; j++) {
        float key = __fmaf_rn(kx, Qx[j], __fmaf_rn(ky, Qy[j], __fmaf_rn(kz, Qz[j], p.w)));
        dmin[j] = fminf(dmin[j], key);
      }
    }
  }
  __syncthreads();
  float* dl = (float*)Pst;
#pragma unroll
  for (int j = 0; j < 16; j++) dl[j * 256 + wave * 64 + lane] = dmin[j];
  if (tid < 16) cnt[tid] = 0;
  __syncthreads();
#pragma unroll 1
  for (int jj = 0; jj < 4; jj++) {
    int j = wave * 4 + jj;
    float v = fminf(fminf(dl[j * 256 + lane], dl[j * 256 + 64 + lane]),
                    fminf(dl[j * 256 + 128 + lane], dl[j * 256 + 192 + lane]));
#pragma unroll
    for (int k = 2; k <= 64; k <<= 1)
#pragma unroll
      for (int s = k >> 1; s > 0; s >>= 1) {
        float o = __shfl_xor(v, s);
        bool up = ((lane & k) == 0);
        bool tmin = (((lane & s) == 0) == up);
        v = tmin ? fminf(v, o) : fmaxf(v, o);
      }
    if (lane == 31) Tsh[j] = v;
  }
  __syncthreads();
  float T[16];
#pragma unroll
  for (int j = 0; j < 16; j++) T[j] = Tsh[j];
  for (int c = 0; c < N_ / 1024; c++) {
    __syncthreads();
#pragma unroll
    for (int u = 0; u < 4; u++) Pst[tid + u * 256] = P[c * 1024 + tid + u * 256];
    __syncthreads();
#pragma unroll 1
    for (int t = 0; t < 4; t++) {
      int n = c * 1024 + wave * 256 + t * 64 + lane;
      float4 p = Pst[wave * 256 + t * 64 + lane];
      float kx = -2.0f * p.x, ky = -2.0f * p.y, kz = -2.0f * p.z;
#pragma unroll
      for (int j = 0; j < 16; j++) {
        float key = __fmaf_rn(kx, Qx[j], __fmaf_rn(ky, Qy[j], __fmaf_rn(kz, Qz[j], p.w)));
        bool pred = key <= T[j];
        unsigned long long mask = __ballot(pred);
        if (mask) {
          int basew;
          if (lane == 0) basew = atomicAdd(&cnt[j], (int)__popcll(mask));
          basew = __shfl(basew, 0);
          if (pred) {
            int off = basew + (int)__popcll(mask & ((1ull << lane) - 1ull));
            if (off < 256) surv[j][off] = (unsigned short)n;
          }
        }
      }
    }
  }
  __syncthreads();
#pragma unroll 1
  for (int jj = 0; jj < 4; jj++) {
    int j = wave * 4 + jj;
    float4 Q = qw[b * NP_ + q0 + j];
    int m = cnt[j] < 256 ? cnt[j] : 256;
    if (m <= 64) {
      unsigned long long v = ~0ull;
      if (lane < m) {
        int n = surv[j][lane];
        float4 p = P[n];
        float d2 = d2_ref(Q, p);
        v = ((unsigned long long)fmono(d2) << 32) | (unsigned int)n;
      }
#pragma unroll
      for (int k = 2; k <= 64; k <<= 1)
#pragma unroll
        for (int s = k >> 1; s > 0; s >>= 1) {
          unsigned long long o = __shfl_xor(v, s);
          bool up = ((lane & k) == 0);
          bool tmin = (((lane & s) == 0) == up);
          unsigned long long lo = v < o ? v : o;
          unsigned long long hi = v < o ? o : v;
          v = tmin ? lo : hi;
        }
      if (lane < 32) idx_out[(b * NP_ + q0 + j) * NS_ + lane] = (int)(v & 0xFFFFu);
    } else {
      unsigned long long k4[4];
#pragma unroll
      for (int t = 0; t < 4; t++) {
        int ii = t * 64 + lane;
        k4[t] = ~0ull;
        if (ii < m) {
          int n = surv[j][ii];
          float4 p = P[n];
          float d2 = d2_ref(Q, p);
          k4[t] = ((unsigned long long)fmono(d2) << 32) | (unsigned int)n;
        }
      }
      int keep = 0;
      for (int r = 0; r < 32; r++) {
        unsigned long long loc = k4[0];
        loc = k4[1] < loc ? k4[1] : loc;
        loc = k4[2] < loc ? k4[2] : loc;
        loc = k4[3] < loc ? k4[3] : loc;
        unsigned long long km = wredmin64(loc);
#pragma unroll
        for (int t = 0; t < 4; t++) if (k4[t] == km) k4[t] = ~0ull;
        if (lane == r) keep = (int)(km & 0xFFFFu);
      }
      if (lane < 32) idx_out[(b * NP_ + q0 + j) * NS_ + lane] = keep;
    }
  }
}

// ---------- fused1: gather + GEMM1 -> stats1, write h1 (pre-BN, bf16) (r5 verbatim) ----------
__global__ __launch_bounds__(256, 4) void fused1_mat(
    const int* __restrict__ idx, const float4* __restrict__ xyzw, const float4* __restrict__ qw,
    const unsigned short* __restrict__ pTb, const unsigned short* __restrict__ W1b,
    const float* __restrict__ b1, float* __restrict__ statsOut, unsigned short* __restrict__ h) {
  __shared__ unsigned short W1L[64 * 104];
  __shared__ unsigned short hbuf[64 * 64];
  __shared__ float sAcc[128];
  int tid = threadIdx.x;
  int w = tid >> 6, l = tid & 63;
  int c16 = l & 15, g = l >> 4;
  for (int e = tid; e < 64 * 12; e += 256) {
    int r = e / 12, c = e % 12;
    *(uint4*)&W1L[r * 104 + c * 8] = *(const uint4*)&W1b[r * 96 + c * 8];
  }
  float rb1[4];
#pragma unroll
  for (int j = 0; j < 4; j++) rb1[j] = b1[j * 16 + c16];
  float st1[4] = {0, 0, 0, 0}, st2[4] = {0, 0, 0, 0};
  __syncthreads();
  for (int tile = blockIdx.x; tile < S_ / 64; tile += gridDim.x) {
    int b = tile >> 10;
    int s = tile * 64 + w * 16 + c16;
    int n = idx[s] & (N_ - 1);
    const unsigned short* arow = pTb + (((size_t)(b << 14) + n) << 6);
    bf8_t a0 = ld_bf8(arow + g * 8);
    bf8_t a1 = ld_bf8(arow + 32 + g * 8);
    float4 P = xyzw[(b << 14) + n];
    float4 Q = qw[tile * 2 + (w >> 1)];
    bf8_t a2 = {0, 0, 0, 0, 0, 0, 0, 0};
    if (g == 0) {
      a2[0] = (short)f2bf(P.x - Q.x);
      a2[1] = (short)f2bf(P.y - Q.y);
      a2[2] = (short)f2bf(P.z - Q.z);
    }
    f4_t acc1[4];
#pragma unroll
    for (int j = 0; j < 4; j++) {
      bf8_t w0 = ld_bf8(&W1L[(j * 16 + c16) * 104 + 0 * 32 + g * 8]);
      bf8_t w1 = ld_bf8(&W1L[(j * 16 + c16) * 104 + 1 * 32 + g * 8]);
      bf8_t w2 = ld_bf8(&W1L[(j * 16 + c16) * 104 + 2 * 32 + g * 8]);
      acc1[j] = (f4_t){0.0f, 0.0f, 0.0f, 0.0f};
      acc1[j] = MFMA16(a0, w0, acc1[j]);
      acc1[j] = MFMA16(a1, w1, acc1[j]);
      acc1[j] = MFMA16(a2, w2, acc1[j]);
    }
    __syncthreads();
#pragma unroll
    for (int j = 0; j < 4; j++)
#pragma unroll
      for (int r = 0; r < 4; r++) {
        float hv = acc1[j][r] + rb1[j];
        st1[j] += hv; st2[j] += hv * hv;
        int row = w * 16 + g * 4 + r, ch = j * 16 + c16;
        hbuf[row * 64 + (((ch >> 3) ^ (row & 7)) << 3) + (ch & 7)] = f2bf(hv);
      }
    __syncthreads();
    int rrow = w * 16 + c16;
    uint4 v0 = *(const uint4*)&hbuf[rrow * 64 + ((g ^ (rrow & 7)) << 3)];
    uint4 v1 = *(const uint4*)&hbuf[rrow * 64 + (((4 + g) ^ (rrow & 7)) << 3)];
    uint4* hd = (uint4*)(h + (((size_t)tile * 64 + rrow) << 6));
    hd[g] = v0;
    hd[4 + g] = v1;
  }
  __syncthreads();
  if (tid < 128) sAcc[tid] = 0.0f;
  __syncthreads();
#pragma unroll
  for (int j = 0; j < 4; j++) {
    atomicAdd(&sAcc[j * 16 + c16], st1[j]);
    atomicAdd(&sAcc[64 + j * 16 + c16], st2[j]);
  }
  __syncthreads();
  if (tid < 128) atomicAdd(&statsOut[tid], sAcc[tid]);
}

// ---------- fused2: read h1 + BN1/ReLU + GEMM2 -> stats2 ONLY (no h2 write, no barriers) ----------
__global__ __launch_bounds__(256, 4) void fused2_stats(
    const unsigned short* __restrict__ W2b, const float* __restrict__ g1, const float* __restrict__ be1,
    const float* __restrict__ stats1, const float* __restrict__ b2,
    float* __restrict__ statsOut, const unsigned short* __restrict__ h) {
  __shared__ unsigned short W2L[64 * 72];
  __shared__ float sa1[64], sd1[64];
  __shared__ float sAcc[128];
  int tid = threadIdx.x;
  int w = tid >> 6, l = tid & 63;
  int c16 = l & 15, g = l >> 4;
  for (int e = tid; e < 64 * 8; e += 256) {
    int r = e >> 3, c = e & 7;
    *(uint4*)&W2L[r * 72 + c * 8] = *(const uint4*)&W2b[r * 64 + c * 8];
  }
  if (tid < 64) {
    float m = stats1[tid] * INV_CNT;
    float v = stats1[64 + tid] * INV_CNT - m * m;
    float a = rsqrtf(v + 1e-5f) * g1[tid];
    sa1[tid] = a;
    sd1[tid] = be1[tid] - m * a;
  }
  float rb2[4];
#pragma unroll
  for (int j = 0; j < 4; j++) rb2[j] = b2[j * 16 + c16];
  float st1[4] = {0, 0, 0, 0}, st2[4] = {0, 0, 0, 0};
  __syncthreads();
  for (int tile = blockIdx.x; tile < S_ / 64; tile += gridDim.x) {
    int rrow = w * 16 + c16;
    const uint4* hd = (const uint4*)(h + (((size_t)tile * 64 + rrow) << 6));
    u4s8 c0, c1;
    c0.u = hd[g];
    c1.u = hd[4 + g];
    bf8_t a0f, a1f;
#pragma unroll
    for (int e = 0; e < 8; e++) {
      a0f[e] = (short)f2bf(fmaxf(0.0f, fmaf(bf2f(c0.s[e]), sa1[g * 8 + e], sd1[g * 8 + e])));
      a1f[e] = (short)f2bf(fmaxf(0.0f, fmaf(bf2f(c1.s[e]), sa1[32 + g * 8 + e], sd1[32 + g * 8 + e])));
    }
#pragma unroll
    for (int j = 0; j < 4; j++) {
      bf8_t w0 = ld_bf8(&W2L[(j * 16 + c16) * 72 + g * 8]);
      bf8_t w1 = ld_bf8(&W2L[(j * 16 + c16) * 72 + 32 + g * 8]);
      f4_t acc = (f4_t){0.0f, 0.0f, 0.0f, 0.0f};
      acc = MFMA16(a0f, w0, acc);
      acc = MFMA16(a1f, w1, acc);
#pragma unroll
      for (int r = 0; r < 4; r++) {
        float hv = acc[r] + rb2[j];
        st1[j] += hv; st2[j] += hv * hv;
      }
    }
  }
  __syncthreads();
  if (tid < 128) sAcc[tid] = 0.0f;
  __syncthreads();
#pragma unroll
  for (int j = 0; j < 4; j++) {
    atomicAdd(&sAcc[j * 16 + c16], st1[j]);
    atomicAdd(&sAcc[64 + j * 16 + c16], st2[j]);
  }
  __syncthreads();
  if (tid < 128) atomicAdd(&statsOut[tid], sAcc[tid]);
}

// ---------- fused3: read h1, recompute GEMM2 (bit-identical), BN2/ReLU, GEMM3 -> stats3 + maxmin ----------
__global__ __launch_bounds__(256, 3) void fused3_mat(
    const unsigned short* __restrict__ W2b, const unsigned short* __restrict__ W3b,
    const float* __restrict__ g1, const float* __restrict__ be1, const float* __restrict__ stats1,
    const float* __restrict__ b2,
    const float* __restrict__ g2, const float* __restrict__ be2, const float* __restrict__ stats2,
    const float* __restrict__ b3,
    float* __restrict__ statsOut, const unsigned short* __restrict__ h, float* __restrict__ maxmin) {
  __shared__ unsigned short W2L[64 * 72];
  __shared__ unsigned short W3L[128 * 72];
  __shared__ unsigned short hbuf[64 * 64];
  __shared__ float sa1[64], sd1[64];
  __shared__ float smx[4][128];
  __shared__ float smn[4][128];
  __shared__ float sAcc[256];
  int tid = threadIdx.x;
  int w = tid >> 6, l = tid & 63;
  int c16 = l & 15, g = l >> 4;
  for (int e = tid; e < 64 * 8; e += 256) {
    int r = e >> 3, c = e & 7;
    *(uint4*)&W2L[r * 72 + c * 8] = *(const uint4*)&W2b[r * 64 + c * 8];
  }
  for (int e = tid; e < 128 * 8; e += 256) {
    int r = e >> 3, c = e & 7;
    *(uint4*)&W3L[r * 72 + c * 8] = *(const uint4*)&W3b[r * 64 + c * 8];
  }
  if (tid < 64) {
    float m = stats1[tid] * INV_CNT;
    float v = stats1[64 + tid] * INV_CNT - m * m;
    float a = rsqrtf(v + 1e-5f) * g1[tid];
    sa1[tid] = a;
    sd1[tid] = be1[tid] - m * a;
  }
  float rb2[4], ra2[4], rd2[4], rb3[8];
#pragma unroll
  for (int j = 0; j < 4; j++) {
    int ch = j * 16 + c16;
    float m = stats2[ch] * INV_CNT;
    float v = stats2[64 + ch] * INV_CNT - m * m;
    float a = rsqrtf(v + 1e-5f) * g2[ch];
    ra2[j] = a; rd2[j] = be2[ch] - m * a;
    rb2[j] = b2[ch];
  }
#pragma unroll
  for (int j = 0; j < 8; j++) rb3[j] = b3[j * 16 + c16];
  float st1[8], st2[8];
#pragma unroll
  for (int j = 0; j < 8; j++) { st1[j] = 0.0f; st2[j] = 0.0f; }
  __syncthreads();
  for (int tile = blockIdx.x; tile < S_ / 64; tile += gridDim.x) {
    int rrow = w * 16 + c16;
    const uint4* hd = (const uint4*)(h + (((size_t)tile * 64 + rrow) << 6));
    u4s8 c0, c1;
    c0.u = hd[g];
    c1.u = hd[4 + g];
    bf8_t a0f, a1f;
#pragma unroll
    for (int e = 0; e < 8; e++) {
      a0f[e] = (short)f2bf(fmaxf(0.0f, fmaf(bf2f(c0.s[e]), sa1[g * 8 + e], sd1[g * 8 + e])));
      a1f[e] = (short)f2bf(fmaxf(0.0f, fmaf(bf2f(c1.s[e]), sa1[32 + g * 8 + e], sd1[32 + g * 8 + e])));
    }
    // GEMM2 (recompute, bit-identical to fused2_stats)
    f4_t acc2[4];
#pragma unroll
    for (int j = 0; j < 4; j++) {
      bf8_t w0 = ld_bf8(&W2L[(j * 16 + c16) * 72 + g * 8]);
      bf8_t w1 = ld_bf8(&W2L[(j * 16 + c16) * 72 + 32 + g * 8]);
      acc2[j] = (f4_t){0.0f, 0.0f, 0.0f, 0.0f};
      acc2[j] = MFMA16(a0f, w0, acc2[j]);
      acc2[j] = MFMA16(a1f, w1, acc2[j]);
    }
    __syncthreads();   // B1: prior tile's hbuf reads complete
#pragma unroll
    for (int j = 0; j < 4; j++)
#pragma unroll
      for (int r = 0; r < 4; r++) {
        float h2 = acc2[j][r] + rb2[j];
        float t = fmaxf(0.0f, fmaf(h2, ra2[j], rd2[j]));
        int row = w * 16 + g * 4 + r, ch = j * 16 + c16;
        hbuf[row * 64 + (((ch >> 3) ^ (row & 7)) << 3) + (ch & 7)] = f2bf(t);
      }
    __syncthreads();   // B2
    bf8_t h2f[2];
#pragma unroll
    for (int kb = 0; kb < 2; kb++)
      h2f[kb] = ld_bf8(hbuf + rrow * 64 + (((kb * 4 + g) ^ (rrow & 7)) << 3));
    float mx[8], mn[8];
#pragma unroll
    for (int j = 0; j < 8; j++) { mx[j] = -1e30f; mn[j] = 1e30f; }
#pragma unroll
    for (int j = 0; j < 8; j++) {
      bf8_t w0 = ld_bf8(&W3L[(j * 16 + c16) * 72 + g * 8]);
      bf8_t w1 = ld_bf8(&W3L[(j * 16 + c16) * 72 + 32 + g * 8]);
      f4_t acc = (f4_t){0.0f, 0.0f, 0.0f, 0.0f};
      acc = MFMA16(h2f[0], w0, acc);
      acc = MFMA16(h2f[1], w1, acc);
#pragma unroll
      for (int r = 0; r < 4; r++) {
        float hv = acc[r] + rb3[j];
        st1[j] += hv; st2[j] += hv * hv;
        mx[j] = fmaxf(mx[j], hv); mn[j] = fminf(mn[j], hv);
      }
      mx[j] = fmaxf(mx[j], __shfl_xor(mx[j], 16));
      mx[j] = fmaxf(mx[j], __shfl_xor(mx[j], 32));
      mn[j] = fminf(mn[j], __shfl_xor(mn[j], 16));
      mn[j] = fminf(mn[j], __shfl_xor(mn[j], 32));
    }
    if (l < 16) {
#pragma unroll
      for (int j = 0; j < 8; j++) { smx[w][j * 16 + l] = mx[j]; smn[w][j * 16 + l] = mn[j]; }
    }
    __syncthreads();   // B3
    {
      int cen = tid >> 7, ch = tid & 127;
      float vx = fmaxf(smx[2 * cen][ch], smx[2 * cen + 1][ch]);
      float vn = fminf(smn[2 * cen][ch], smn[2 * cen + 1][ch]);
      size_t gcen = (size_t)tile * 2 + cen;
      maxmin[gcen * 256 + ch * 2 + 0] = vx;
      maxmin[gcen * 256 + ch * 2 + 1] = vn;
    }
  }
  __syncthreads();
  if (tid < 256) sAcc[tid] = 0.0f;
  __syncthreads();
#pragma unroll
  for (int j = 0; j < 8; j++) {
    atomicAdd(&sAcc[j * 16 + c16], st1[j]);
    atomicAdd(&sAcc[128 + j * 16 + c16], st2[j]);
  }
  __syncthreads();
  if (tid < 256) atomicAdd(&statsOut[tid], sAcc[tid]);
}

// ---------- finalize: BN3 affine on max/min -> (B,128,NP) ----------
__global__ __launch_bounds__(256) void finalize_kernel(const float* __restrict__ maxmin,
                                                       const float* __restrict__ stats3,
                                                       const float* __restrict__ g3, const float* __restrict__ be3,
                                                       float* __restrict__ out_np) {
  int o = blockIdx.x * 256 + threadIdx.x;   // B*128*NP
  int p = o & 2047, ch = (o >> 11) & 127, b = o >> 18;
  float m = stats3[ch] * INV_CNT;
  float v = stats3[128 + ch] * INV_CNT - m * m;
  float a = rsqrtf(v + 1e-5f) * g3[ch];
  float d = be3[ch] - m * a;
  size_t g = (size_t)(b * 2048 + p);
  float hi = maxmin[g * 256 + ch * 2 + 0];
  float lo = maxmin[g * 256 + ch * 2 + 1];
  out_np[o] = fmaf(a, (a >= 0.0f ? hi : lo), d);
}

// ---------- launcher ----------
extern "C" void kernel_launch(void* const* d_in, const int* in_sizes, int n_in,
                              void* d_out, int out_size, void* d_ws, size_t ws_size,
                              hipStream_t stream) {
  const float* xyz = (const float*)d_in[0];
  const float* points = (const float*)d_in[1];
  const int* sidx = (const int*)d_in[2];
  const float* W1 = (const float*)d_in[3];
  const float* b1 = (const float*)d_in[4];
  const float* g1 = (const float*)d_in[5];
  const float* be1 = (const float*)d_in[6];
  const float* W2 = (const float*)d_in[7];
  const float* b2 = (const float*)d_in[8];
  const float* g2 = (const float*)d_in[9];
  const float* be2 = (const float*)d_in[10];
  const float* W3 = (const float*)d_in[11];
  const float* b3 = (const float*)d_in[12];
  const float* g3 = (const float*)d_in[13];
  const float* be3 = (const float*)d_in[14];

  float* out_q = (float*)d_out;
  float* out_np = (float*)d_out + (size_t)B_ * 3 * NP_;

  char* ws = (char*)d_ws;
  float* stats1 = (float*)(ws + 0);      // 128 f32
  float* stats2 = (float*)(ws + 512);    // 128 f32
  float* stats3 = (float*)(ws + 1024);   // 256 f32
  size_t off = 4096;
  float4* xyzw = (float4*)(ws + off); off += (size_t)B_ * N_ * 16;              // 2 MB
  float4* qw = (float4*)(ws + off);   off += (size_t)B_ * NP_ * 16;             // 256 KB
  int* idxb = (int*)(ws + off);       off += (size_t)B_ * NP_ * NS_ * 4;        // 2 MB
  unsigned short* pTb = (unsigned short*)(ws + off); off += (size_t)B_ * N_ * 64 * 2;  // 16 MB
  unsigned short* W1b = (unsigned short*)(ws + off); off += 64 * 96 * 2;
  unsigned short* W2b = (unsigned short*)(ws + off); off += 64 * 64 * 2;
  unsigned short* W3b = (unsigned short*)(ws + off); off += 128 * 64 * 2;
  float* maxmin = (float*)(ws + off);  off += (size_t)B_ * NP_ * 128 * 2 * 4;   // 16 MB
  unsigned short* hG = (unsigned short*)(ws + off); off += (size_t)S_ * 64 * 2; // 64 MiB

  hipMemsetAsync(ws, 0, 4096, stream);
  prep_xyzw<<<B_ * N_ / 256, 256, 0, stream>>>(xyz, xyzw);
  prep_q<<<B_ * NP_ / 256, 256, 0, stream>>>(sidx, xyzw, qw, out_q);
  transpose_bf16<<<B_ * 2 * (N_ / 32), 256, 0, stream>>>(points, pTb);
  prep_w<<<72, 256, 0, stream>>>(W1, W2, W3, W1b, W2b, W3b);
  knn_kernel<<<B_ * (NP_ / 16), 256, 0, stream>>>(xyzw, qw, idxb);
  fused1_mat<<<1024, 256, 0, stream>>>(idxb, xyzw, qw, pTb, W1b, b1, stats1, hG);
  fused2_stats<<<1024, 256, 0, stream>>>(W2b, g1, be1, stats1, b2, stats2, hG);
  fused3_mat<<<768, 256, 0, stream>>>(W2b, W3b, g1, be1, stats1, b2, g2, be2, stats2, b3,
                                      stats3, hG, maxmin);
  finalize_kernel<<<(B_ * 128 * NP_) / 256, 256, 0, stream>>>(maxmin, stats3, g3, be3, out_np);
}